// Round 3
// baseline (243.294 us; speedup 1.0000x reference)
//
#include <hip/hip_runtime.h>
#include <cstdint>

#define NQ 8
#define NKV 16
#define NPAIR 160   // 128 qk partials + 32 per-wave norm partials (4 waves x 8 rows)

// ---------------- Threefry-2x32 (exact JAX implementation) ----------------
__device__ __forceinline__ unsigned rotl32(unsigned x, int d) {
    return (x << d) | (x >> (32 - d));
}

__device__ __forceinline__ void threefry2x32(unsigned k0, unsigned k1,
                                             unsigned& x0, unsigned& x1) {
    const unsigned ks0 = k0, ks1 = k1, ks2 = k0 ^ k1 ^ 0x1BD11BDAu;
    x0 += ks0; x1 += ks1;
    // group 1 (rot set 0: 13,15,26,6)
    x0 += x1; x1 = rotl32(x1, 13); x1 ^= x0;
    x0 += x1; x1 = rotl32(x1, 15); x1 ^= x0;
    x0 += x1; x1 = rotl32(x1, 26); x1 ^= x0;
    x0 += x1; x1 = rotl32(x1,  6); x1 ^= x0;
    x0 += ks1; x1 += ks2 + 1u;
    // group 2 (rot set 1: 17,29,16,24)
    x0 += x1; x1 = rotl32(x1, 17); x1 ^= x0;
    x0 += x1; x1 = rotl32(x1, 29); x1 ^= x0;
    x0 += x1; x1 = rotl32(x1, 16); x1 ^= x0;
    x0 += x1; x1 = rotl32(x1, 24); x1 ^= x0;
    x0 += ks2; x1 += ks0 + 2u;
    // group 3 (rot set 0)
    x0 += x1; x1 = rotl32(x1, 13); x1 ^= x0;
    x0 += x1; x1 = rotl32(x1, 15); x1 ^= x0;
    x0 += x1; x1 = rotl32(x1, 26); x1 ^= x0;
    x0 += x1; x1 = rotl32(x1,  6); x1 ^= x0;
    x0 += ks0; x1 += ks1 + 3u;
    // group 4 (rot set 1)
    x0 += x1; x1 = rotl32(x1, 17); x1 ^= x0;
    x0 += x1; x1 = rotl32(x1, 29); x1 ^= x0;
    x0 += x1; x1 = rotl32(x1, 16); x1 ^= x0;
    x0 += x1; x1 = rotl32(x1, 24); x1 ^= x0;
    x0 += ks1; x1 += ks2 + 4u;
    // group 5 (rot set 0)
    x0 += x1; x1 = rotl32(x1, 13); x1 ^= x0;
    x0 += x1; x1 = rotl32(x1, 15); x1 ^= x0;
    x0 += x1; x1 = rotl32(x1, 26); x1 ^= x0;
    x0 += x1; x1 = rotl32(x1,  6); x1 ^= x0;
    x0 += ks2; x1 += ks0 + 5u;
}

// keep-bit for flattened index idx in [0,128): matches
// jax.random.bernoulli(jax.random.key(42), 0.9, (8,16)) under the MODERN
// default jax_threefry_partitionable=True:
//   counter = uint64(idx); x0 = hi32 = 0, x1 = lo32 = idx
//   (o0,o1) = threefry2x32((0,42), x0, x1);  bits32 = o0 ^ o1
__device__ __forceinline__ int jax_keep_bit(int idx) {
    unsigned x0 = 0u, x1 = (unsigned)idx;
    threefry2x32(0u, 42u, x0, x1);
    unsigned bits = x0 ^ x1;
    unsigned fb = (bits >> 9) | 0x3F800000u;
    float u = __uint_as_float(fb) - 1.0f;
    return u < 0.9f ? 1 : 0;
}

// ---------------- Phase 1: partial dot products ----------------
// Block grid-strides over 256-float4 column chunks. q rows (8) staged in LDS
// by all threads; wave w then sweeps ALL 256 columns (4 sub-passes of 64
// lanes) dotting q against its 4 kv rows. Every HBM byte read exactly once.
__global__ __launch_bounds__(256) void qk_partial_kernel(
    const float4* __restrict__ qkv, float* __restrict__ partial,
    int D4, int nblocks)
{
    __shared__ float4 qs[NQ][256];
    const int tid  = threadIdx.x;
    const int w    = tid >> 6;   // wave id 0..3
    const int lane = tid & 63;
    const int bid  = blockIdx.x;

    float acc[NQ][4];
#pragma unroll
    for (int r = 0; r < NQ; ++r)
#pragma unroll
        for (int jj = 0; jj < 4; ++jj) acc[r][jj] = 0.f;
    float nacc[NQ];
#pragma unroll
    for (int r = 0; r < NQ; ++r) nacc[r] = 0.f;

    const long long stride = (long long)nblocks * 256;

    for (long long base = (long long)bid * 256; base < (long long)D4;
         base += stride) {
        const long long v = base + tid;
        const bool valid = v < (long long)D4;

        __syncthreads();  // protect LDS from previous iteration's readers
#pragma unroll
        for (int r = 0; r < NQ; ++r) {
            const float4 qv = valid ? qkv[(long long)r * D4 + v]
                                    : make_float4(0.f, 0.f, 0.f, 0.f);
            qs[r][tid] = qv;
            // every thread owns one column -> summed over block = full ||q||^2
            nacc[r] += qv.x * qv.x + qv.y * qv.y + qv.z * qv.z + qv.w * qv.w;
        }
        __syncthreads();

#pragma unroll
        for (int sub = 0; sub < 4; ++sub) {
            const long long col = base + sub * 64 + lane;
            const bool cvalid = col < (long long)D4;
            float4 kvv[4];
#pragma unroll
            for (int jj = 0; jj < 4; ++jj)
                kvv[jj] = cvalid
                    ? qkv[(long long)(NQ + w * 4 + jj) * D4 + col]
                    : make_float4(0.f, 0.f, 0.f, 0.f);
#pragma unroll
            for (int r = 0; r < NQ; ++r) {
                const float4 qv = qs[r][sub * 64 + lane];
#pragma unroll
                for (int jj = 0; jj < 4; ++jj) {
                    acc[r][jj] += qv.x * kvv[jj].x + qv.y * kvv[jj].y +
                                  qv.z * kvv[jj].z + qv.w * kvv[jj].w;
                }
            }
        }
    }

    // wave-level reduction, lane 0 writes
#pragma unroll
    for (int r = 0; r < NQ; ++r) {
#pragma unroll
        for (int jj = 0; jj < 4; ++jj) {
            float vsum = acc[r][jj];
            for (int off = 32; off >= 1; off >>= 1)
                vsum += __shfl_xor(vsum, off, 64);
            if (lane == 0)
                partial[(long long)bid * NPAIR + r * NKV + (w * 4 + jj)] = vsum;
        }
    }
#pragma unroll
    for (int r = 0; r < NQ; ++r) {
        float vsum = nacc[r];
        for (int off = 32; off >= 1; off >>= 1)
            vsum += __shfl_xor(vsum, off, 64);
        if (lane == 0)
            partial[(long long)bid * NPAIR + 128 + w * NQ + r] = vsum;
    }
}

// ---------------- Phase 2: reduce partials across blocks ----------------
__global__ __launch_bounds__(256) void reduce_kernel(
    const float* __restrict__ partial, float* __restrict__ sums, int nblocks)
{
    const int s = blockIdx.x;  // 0..159
    float acc = 0.f;
    for (int b = threadIdx.x; b < nblocks; b += 256)
        acc += partial[(long long)b * NPAIR + s];

    float vsum = acc;
    for (int off = 32; off >= 1; off >>= 1)
        vsum += __shfl_xor(vsum, off, 64);

    __shared__ float red[4];
    const int w = threadIdx.x >> 6, lane = threadIdx.x & 63;
    if (lane == 0) red[w] = vsum;
    __syncthreads();
    if (threadIdx.x == 0) sums[s] = red[0] + red[1] + red[2] + red[3];
}

// ---------------- Phase 3: scale, softmax, dropout ----------------
__global__ __launch_bounds__(128) void finalize_kernel(
    const float* __restrict__ sums, float* __restrict__ out)
{
    const int idx = threadIdx.x;           // 0..127
    const int r = idx >> 4;                // q row

    const float norm = sums[128 + r] + sums[128 + NQ + r] +
                       sums[128 + 2 * NQ + r] + sums[128 + 3 * NQ + r];
    const float inv_scale = rsqrtf(norm + 1e-12f);
    const float logit = sums[idx] * inv_scale;

    // rows are 16-lane groups inside a wave
    float m = logit;
    for (int off = 8; off >= 1; off >>= 1)
        m = fmaxf(m, __shfl_xor(m, off, 64));
    const float e = expf(logit - m);
    float ssum = e;
    for (int off = 8; off >= 1; off >>= 1)
        ssum += __shfl_xor(ssum, off, 64);
    const float sm = e / ssum;

    const int keep = jax_keep_bit(idx);
    out[idx] = keep ? (sm / 0.9f) : 0.f;
}

// ---------------- Launch ----------------
extern "C" void kernel_launch(void* const* d_in, const int* in_sizes, int n_in,
                              void* d_out, int out_size, void* d_ws, size_t ws_size,
                              hipStream_t stream) {
    const float* qkv = (const float*)d_in[0];
    float* out = (float*)d_out;

    const long long total = (long long)in_sizes[0];
    const int D  = (int)(total / (NQ + NKV));
    const int D4 = D / 4;

    float* wsf = (float*)d_ws;
    const long long cap_floats = (long long)(ws_size / 4);

    int nblocks = 1024;
    long long need = (long long)nblocks * NPAIR + NPAIR;
    if (need > cap_floats) {
        nblocks = (int)((cap_floats - NPAIR) / NPAIR);
        if (nblocks < 1) nblocks = 1;
    }

    float* partial = wsf;
    float* sums    = wsf + (long long)nblocks * NPAIR;

    qk_partial_kernel<<<nblocks, 256, 0, stream>>>(
        (const float4*)qkv, partial, D4, nblocks);
    reduce_kernel<<<NPAIR, 256, 0, stream>>>(partial, sums, nblocks);
    finalize_kernel<<<1, 128, 0, stream>>>(sums, out);
}

// Round 4
// 139.877 us; speedup vs baseline: 1.7393x; 1.7393x over previous
//
#include <hip/hip_runtime.h>
#include <cstdint>

#define NQ 8
#define NKV 16
#define NPAIR 136   // 128 qk partials + 8 norm partials

// ---------------- Threefry-2x32 (JAX partitionable path) ----------------
__device__ __forceinline__ unsigned rotl32(unsigned x, int d) {
    return (x << d) | (x >> (32 - d));
}

__device__ __forceinline__ void threefry2x32(unsigned k0, unsigned k1,
                                             unsigned& x0, unsigned& x1) {
    const unsigned ks0 = k0, ks1 = k1, ks2 = k0 ^ k1 ^ 0x1BD11BDAu;
    x0 += ks0; x1 += ks1;
    x0 += x1; x1 = rotl32(x1, 13); x1 ^= x0;
    x0 += x1; x1 = rotl32(x1, 15); x1 ^= x0;
    x0 += x1; x1 = rotl32(x1, 26); x1 ^= x0;
    x0 += x1; x1 = rotl32(x1,  6); x1 ^= x0;
    x0 += ks1; x1 += ks2 + 1u;
    x0 += x1; x1 = rotl32(x1, 17); x1 ^= x0;
    x0 += x1; x1 = rotl32(x1, 29); x1 ^= x0;
    x0 += x1; x1 = rotl32(x1, 16); x1 ^= x0;
    x0 += x1; x1 = rotl32(x1, 24); x1 ^= x0;
    x0 += ks2; x1 += ks0 + 2u;
    x0 += x1; x1 = rotl32(x1, 13); x1 ^= x0;
    x0 += x1; x1 = rotl32(x1, 15); x1 ^= x0;
    x0 += x1; x1 = rotl32(x1, 26); x1 ^= x0;
    x0 += x1; x1 = rotl32(x1,  6); x1 ^= x0;
    x0 += ks0; x1 += ks1 + 3u;
    x0 += x1; x1 = rotl32(x1, 17); x1 ^= x0;
    x0 += x1; x1 = rotl32(x1, 29); x1 ^= x0;
    x0 += x1; x1 = rotl32(x1, 16); x1 ^= x0;
    x0 += x1; x1 = rotl32(x1, 24); x1 ^= x0;
    x0 += ks1; x1 += ks2 + 4u;
    x0 += x1; x1 = rotl32(x1, 13); x1 ^= x0;
    x0 += x1; x1 = rotl32(x1, 15); x1 ^= x0;
    x0 += x1; x1 = rotl32(x1, 26); x1 ^= x0;
    x0 += x1; x1 = rotl32(x1,  6); x1 ^= x0;
    x0 += ks2; x1 += ks0 + 5u;
}

// matches jax.random.bernoulli(jax.random.key(42), 0.9, (8,16)) with
// jax_threefry_partitionable=True (verified by R3 pass, absmax 0.0)
__device__ __forceinline__ int jax_keep_bit(int idx) {
    unsigned x0 = 0u, x1 = (unsigned)idx;
    threefry2x32(0u, 42u, x0, x1);
    unsigned bits = x0 ^ x1;
    unsigned fb = (bits >> 9) | 0x3F800000u;
    float u = __uint_as_float(fb) - 1.0f;
    return u < 0.9f ? 1 : 0;
}

// ---------------- Phase 1: partial dot products (no LDS, no barriers) ----
// Each thread owns float4-columns via grid-stride; per column it loads all
// 24 row values (8 q + 16 kv) -- 24 independent 16B loads -- and accumulates
// all 128 products + 8 squares in registers. Every HBM byte read once.
__global__ __launch_bounds__(256) void qk_partial_kernel(
    const float4* __restrict__ qkv, float* __restrict__ partial,
    int D4, int nblocks)
{
    const int tid  = threadIdx.x;
    const int w    = tid >> 6;
    const int lane = tid & 63;
    const int bid  = blockIdx.x;

    float acc[NQ][NKV];
#pragma unroll
    for (int r = 0; r < NQ; ++r)
#pragma unroll
        for (int j = 0; j < NKV; ++j) acc[r][j] = 0.f;
    float nacc[NQ];
#pragma unroll
    for (int r = 0; r < NQ; ++r) nacc[r] = 0.f;

    const long long stride = (long long)nblocks * 256;

    for (long long v = (long long)bid * 256 + tid; v < (long long)D4;
         v += stride) {
        float4 qv[NQ];
#pragma unroll
        for (int r = 0; r < NQ; ++r)
            qv[r] = qkv[(long long)r * D4 + v];
        float4 kv[NKV];
#pragma unroll
        for (int j = 0; j < NKV; ++j)
            kv[j] = qkv[(long long)(NQ + j) * D4 + v];

#pragma unroll
        for (int r = 0; r < NQ; ++r) {
            nacc[r] += qv[r].x * qv[r].x + qv[r].y * qv[r].y +
                       qv[r].z * qv[r].z + qv[r].w * qv[r].w;
#pragma unroll
            for (int j = 0; j < NKV; ++j) {
                acc[r][j] += qv[r].x * kv[j].x + qv[r].y * kv[j].y +
                             qv[r].z * kv[j].z + qv[r].w * kv[j].w;
            }
        }
    }

    // wave-level shuffle reduction of all 136 values
    __shared__ float lred[4][NPAIR];
#pragma unroll
    for (int r = 0; r < NQ; ++r) {
#pragma unroll
        for (int j = 0; j < NKV; ++j) {
            float s = acc[r][j];
#pragma unroll
            for (int off = 32; off >= 1; off >>= 1)
                s += __shfl_xor(s, off, 64);
            if (lane == 0) lred[w][r * NKV + j] = s;
        }
    }
#pragma unroll
    for (int r = 0; r < NQ; ++r) {
        float s = nacc[r];
#pragma unroll
        for (int off = 32; off >= 1; off >>= 1)
            s += __shfl_xor(s, off, 64);
        if (lane == 0) lred[w][128 + r] = s;
    }
    __syncthreads();
    // cross-wave combine: threads 0..135 each own one slot
    if (tid < NPAIR) {
        const float s = lred[0][tid] + lred[1][tid] + lred[2][tid] + lred[3][tid];
        partial[(long long)bid * NPAIR + tid] = s;
    }
}

// ---------------- Phase 2: reduce partials across blocks ----------------
__global__ __launch_bounds__(256) void reduce_kernel(
    const float* __restrict__ partial, float* __restrict__ sums, int nblocks)
{
    const int s = blockIdx.x;  // 0..135
    float acc = 0.f;
    for (int b = threadIdx.x; b < nblocks; b += 256)
        acc += partial[(long long)b * NPAIR + s];

    float vsum = acc;
    for (int off = 32; off >= 1; off >>= 1)
        vsum += __shfl_xor(vsum, off, 64);

    __shared__ float red[4];
    const int w = threadIdx.x >> 6, lane = threadIdx.x & 63;
    if (lane == 0) red[w] = vsum;
    __syncthreads();
    if (threadIdx.x == 0) sums[s] = red[0] + red[1] + red[2] + red[3];
}

// ---------------- Phase 3: scale, softmax, dropout ----------------
__global__ __launch_bounds__(128) void finalize_kernel(
    const float* __restrict__ sums, float* __restrict__ out)
{
    const int idx = threadIdx.x;           // 0..127
    const int r = idx >> 4;                // q row

    const float norm = sums[128 + r];
    const float inv_scale = rsqrtf(norm + 1e-12f);
    const float logit = sums[idx] * inv_scale;

    float m = logit;
    for (int off = 8; off >= 1; off >>= 1)
        m = fmaxf(m, __shfl_xor(m, off, 64));
    const float e = expf(logit - m);
    float ssum = e;
    for (int off = 8; off >= 1; off >>= 1)
        ssum += __shfl_xor(ssum, off, 64);
    const float sm = e / ssum;

    const int keep = jax_keep_bit(idx);
    out[idx] = keep ? (sm / 0.9f) : 0.f;
}

// ---------------- Launch ----------------
extern "C" void kernel_launch(void* const* d_in, const int* in_sizes, int n_in,
                              void* d_out, int out_size, void* d_ws, size_t ws_size,
                              hipStream_t stream) {
    const float* qkv = (const float*)d_in[0];
    float* out = (float*)d_out;

    const long long total = (long long)in_sizes[0];
    const int D  = (int)(total / (NQ + NKV));
    const int D4 = D / 4;

    float* wsf = (float*)d_ws;
    const long long cap_floats = (long long)(ws_size / 4);

    int nblocks = 1024;
    long long need = (long long)nblocks * NPAIR + NPAIR;
    if (need > cap_floats) {
        nblocks = (int)((cap_floats - NPAIR) / NPAIR);
        if (nblocks < 1) nblocks = 1;
    }

    float* partial = wsf;
    float* sums    = wsf + (long long)nblocks * NPAIR;

    qk_partial_kernel<<<nblocks, 256, 0, stream>>>(
        (const float4*)qkv, partial, D4, nblocks);
    reduce_kernel<<<NPAIR, 256, 0, stream>>>(partial, sums, nblocks);
    finalize_kernel<<<1, 128, 0, stream>>>(sums, out);
}

// Round 5
// 132.719 us; speedup vs baseline: 1.8331x; 1.0539x over previous
//
#include <hip/hip_runtime.h>
#include <cstdint>

#define NQ 8
#define NKV 16
#define NGRP 4            // kv rows split across 4 block groups
#define KPG (NKV / NGRP)  // 4 kv rows per group
#define NPB 40            // per-block partials: 8x4 products + 8 norms (g0)
#define NSUM 136          // final: 128 qk + 8 norms

// ---------------- Threefry-2x32 (JAX partitionable path; verified R3) ----
__device__ __forceinline__ unsigned rotl32(unsigned x, int d) {
    return (x << d) | (x >> (32 - d));
}

__device__ __forceinline__ void threefry2x32(unsigned k0, unsigned k1,
                                             unsigned& x0, unsigned& x1) {
    const unsigned ks0 = k0, ks1 = k1, ks2 = k0 ^ k1 ^ 0x1BD11BDAu;
    x0 += ks0; x1 += ks1;
    x0 += x1; x1 = rotl32(x1, 13); x1 ^= x0;
    x0 += x1; x1 = rotl32(x1, 15); x1 ^= x0;
    x0 += x1; x1 = rotl32(x1, 26); x1 ^= x0;
    x0 += x1; x1 = rotl32(x1,  6); x1 ^= x0;
    x0 += ks1; x1 += ks2 + 1u;
    x0 += x1; x1 = rotl32(x1, 17); x1 ^= x0;
    x0 += x1; x1 = rotl32(x1, 29); x1 ^= x0;
    x0 += x1; x1 = rotl32(x1, 16); x1 ^= x0;
    x0 += x1; x1 = rotl32(x1, 24); x1 ^= x0;
    x0 += ks2; x1 += ks0 + 2u;
    x0 += x1; x1 = rotl32(x1, 13); x1 ^= x0;
    x0 += x1; x1 = rotl32(x1, 15); x1 ^= x0;
    x0 += x1; x1 = rotl32(x1, 26); x1 ^= x0;
    x0 += x1; x1 = rotl32(x1,  6); x1 ^= x0;
    x0 += ks0; x1 += ks1 + 3u;
    x0 += x1; x1 = rotl32(x1, 17); x1 ^= x0;
    x0 += x1; x1 = rotl32(x1, 29); x1 ^= x0;
    x0 += x1; x1 = rotl32(x1, 16); x1 ^= x0;
    x0 += x1; x1 = rotl32(x1, 24); x1 ^= x0;
    x0 += ks1; x1 += ks2 + 4u;
    x0 += x1; x1 = rotl32(x1, 13); x1 ^= x0;
    x0 += x1; x1 = rotl32(x1, 15); x1 ^= x0;
    x0 += x1; x1 = rotl32(x1, 26); x1 ^= x0;
    x0 += x1; x1 = rotl32(x1,  6); x1 ^= x0;
    x0 += ks2; x1 += ks0 + 5u;
}

__device__ __forceinline__ int jax_keep_bit(int idx) {
    unsigned x0 = 0u, x1 = (unsigned)idx;
    threefry2x32(0u, 42u, x0, x1);
    unsigned bits = x0 ^ x1;
    unsigned fb = (bits >> 9) | 0x3F800000u;
    float u = __uint_as_float(fb) - 1.0f;
    return u < 0.9f ? 1 : 0;
}

__device__ __forceinline__ float dot4(float4 a, float4 b) {
    return a.x * b.x + a.y * b.y + a.z * b.z + a.w * b.w;
}

// ---------------- Phase 1: partial dots, 4-way kv split -------------------
// blockIdx = cb*4 + g. Group g: all 8 q rows vs kv rows 4g..4g+3.
// acc 8x4 + 8 norms (g0) + 12 float4 staging -> ~100 VGPR, 4 waves/SIMD.
// Groups of one colblock are launch-adjacent -> q re-reads hit L2/L3.
__global__ __launch_bounds__(256, 4) void qk_partial_kernel(
    const float4* __restrict__ qkv, float* __restrict__ partial,
    unsigned D4, unsigned ncb)
{
    const int tid = threadIdx.x;
    const int w   = tid >> 6;
    const int lane = tid & 63;
    const unsigned g  = blockIdx.x & (NGRP - 1);
    const unsigned cb = blockIdx.x >> 2;

    const float4* __restrict__ kbase = qkv + (size_t)(NQ + g * KPG) * D4;

    float acc[NQ][KPG];
#pragma unroll
    for (int r = 0; r < NQ; ++r)
#pragma unroll
        for (int j = 0; j < KPG; ++j) acc[r][j] = 0.f;
    float nacc[NQ];
#pragma unroll
    for (int r = 0; r < NQ; ++r) nacc[r] = 0.f;

    const unsigned stride = ncb * 256u;

    for (unsigned v = cb * 256u + tid; v < D4; v += stride) {
        // kv first, q after: products for row r wait only on qv[r]'s arrival
        float4 kv[KPG];
#pragma unroll
        for (int j = 0; j < KPG; ++j)
            kv[j] = kbase[(size_t)j * D4 + v];
        float4 qv[NQ];
#pragma unroll
        for (int r = 0; r < NQ; ++r)
            qv[r] = qkv[(size_t)r * D4 + v];

        if (g == 0) {
#pragma unroll
            for (int r = 0; r < NQ; ++r)
                nacc[r] += dot4(qv[r], qv[r]);
        }
#pragma unroll
        for (int r = 0; r < NQ; ++r)
#pragma unroll
            for (int j = 0; j < KPG; ++j)
                acc[r][j] += dot4(qv[r], kv[j]);
    }

    // wave shuffle-reduce the 40 partials, then cross-wave combine via LDS
    __shared__ float lred[4][NPB];
#pragma unroll
    for (int r = 0; r < NQ; ++r) {
#pragma unroll
        for (int j = 0; j < KPG; ++j) {
            float s = acc[r][j];
#pragma unroll
            for (int off = 32; off >= 1; off >>= 1)
                s += __shfl_xor(s, off, 64);
            if (lane == 0) lred[w][r * KPG + j] = s;
        }
    }
    if (g == 0) {
#pragma unroll
        for (int r = 0; r < NQ; ++r) {
            float s = nacc[r];
#pragma unroll
            for (int off = 32; off >= 1; off >>= 1)
                s += __shfl_xor(s, off, 64);
            if (lane == 0) lred[w][32 + r] = s;
        }
    } else if (lane == 0) {
#pragma unroll
        for (int r = 0; r < NQ; ++r) lred[w][32 + r] = 0.f;
    }
    __syncthreads();
    if (tid < NPB) {
        const float s = lred[0][tid] + lred[1][tid] + lred[2][tid] + lred[3][tid];
        partial[(size_t)blockIdx.x * NPB + tid] = s;
    }
}

// ---------------- Phase 2: reduce partials across colblocks ---------------
// slot s<128: qk[r][j], r=s>>4, j=s&15 -> group g=j>>2, local jl=j&3
// slot s>=128: norm[s-128] (group-0 blocks only)
__global__ __launch_bounds__(256) void reduce_kernel(
    const float* __restrict__ partial, float* __restrict__ sums, int ncb)
{
    const int s = blockIdx.x;  // 0..135
    int g, slot;
    if (s < 128) {
        const int r = s >> 4, j = s & 15;
        g = j >> 2; slot = r * KPG + (j & 3);
    } else {
        g = 0; slot = 32 + (s - 128);
    }

    float acc = 0.f;
    for (int cb = threadIdx.x; cb < ncb; cb += 256)
        acc += partial[(size_t)(cb * NGRP + g) * NPB + slot];

    float vsum = acc;
    for (int off = 32; off >= 1; off >>= 1)
        vsum += __shfl_xor(vsum, off, 64);

    __shared__ float red[4];
    const int w = threadIdx.x >> 6, lane = threadIdx.x & 63;
    if (lane == 0) red[w] = vsum;
    __syncthreads();
    if (threadIdx.x == 0) sums[s] = red[0] + red[1] + red[2] + red[3];
}

// ---------------- Phase 3: scale, softmax, dropout ------------------------
__global__ __launch_bounds__(128) void finalize_kernel(
    const float* __restrict__ sums, float* __restrict__ out)
{
    const int idx = threadIdx.x;  // 0..127
    const int r = idx >> 4;

    const float norm = sums[128 + r];
    const float inv_scale = rsqrtf(norm + 1e-12f);
    const float logit = sums[idx] * inv_scale;

    float m = logit;
    for (int off = 8; off >= 1; off >>= 1)
        m = fmaxf(m, __shfl_xor(m, off, 64));
    const float e = expf(logit - m);
    float ssum = e;
    for (int off = 8; off >= 1; off >>= 1)
        ssum += __shfl_xor(ssum, off, 64);
    const float sm = e / ssum;

    out[idx] = jax_keep_bit(idx) ? (sm / 0.9f) : 0.f;
}

// ---------------- Launch --------------------------------------------------
extern "C" void kernel_launch(void* const* d_in, const int* in_sizes, int n_in,
                              void* d_out, int out_size, void* d_ws, size_t ws_size,
                              hipStream_t stream) {
    const float* qkv = (const float*)d_in[0];
    float* out = (float*)d_out;

    const long long total = (long long)in_sizes[0];
    const unsigned D  = (unsigned)(total / (NQ + NKV));
    const unsigned D4 = D / 4;

    float* wsf = (float*)d_ws;
    const long long cap_floats = (long long)(ws_size / 4);

    unsigned ncb = 256;  // colblocks; 256*4 groups = 1024 blocks, 1 round
    long long need = (long long)ncb * NGRP * NPB + NSUM;
    while (need > cap_floats && ncb > 1) {
        ncb >>= 1;
        need = (long long)ncb * NGRP * NPB + NSUM;
    }

    float* partial = wsf;
    float* sums    = wsf + (long long)ncb * NGRP * NPB;

    qk_partial_kernel<<<ncb * NGRP, 256, 0, stream>>>(
        (const float4*)qkv, partial, D4, ncb);
    reduce_kernel<<<NSUM, 256, 0, stream>>>(partial, sums, (int)ncb);
    finalize_kernel<<<1, 128, 0, stream>>>(sums, out);
}

// Round 6
// 91.415 us; speedup vs baseline: 2.6614x; 1.4518x over previous
//
#include <hip/hip_runtime.h>
#include <cstdint>

#define NQ 8
#define NKV 16
#define NGRP 4            // kv rows split across 4 block groups
#define KPG (NKV / NGRP)  // 4 kv rows per group
#define NPB 40            // per-block partials: 8x4 products + 8 norms (g0)
#define NSUM 136          // final: 128 qk + 8 norms
#define NXCD 8

// ---------------- Threefry-2x32 (JAX partitionable path; verified R3) ----
__device__ __forceinline__ unsigned rotl32(unsigned x, int d) {
    return (x << d) | (x >> (32 - d));
}

__device__ __forceinline__ void threefry2x32(unsigned k0, unsigned k1,
                                             unsigned& x0, unsigned& x1) {
    const unsigned ks0 = k0, ks1 = k1, ks2 = k0 ^ k1 ^ 0x1BD11BDAu;
    x0 += ks0; x1 += ks1;
    x0 += x1; x1 = rotl32(x1, 13); x1 ^= x0;
    x0 += x1; x1 = rotl32(x1, 15); x1 ^= x0;
    x0 += x1; x1 = rotl32(x1, 26); x1 ^= x0;
    x0 += x1; x1 = rotl32(x1,  6); x1 ^= x0;
    x0 += ks1; x1 += ks2 + 1u;
    x0 += x1; x1 = rotl32(x1, 17); x1 ^= x0;
    x0 += x1; x1 = rotl32(x1, 29); x1 ^= x0;
    x0 += x1; x1 = rotl32(x1, 16); x1 ^= x0;
    x0 += x1; x1 = rotl32(x1, 24); x1 ^= x0;
    x0 += ks2; x1 += ks0 + 2u;
    x0 += x1; x1 = rotl32(x1, 13); x1 ^= x0;
    x0 += x1; x1 = rotl32(x1, 15); x1 ^= x0;
    x0 += x1; x1 = rotl32(x1, 26); x1 ^= x0;
    x0 += x1; x1 = rotl32(x1,  6); x1 ^= x0;
    x0 += ks0; x1 += ks1 + 3u;
    x0 += x1; x1 = rotl32(x1, 17); x1 ^= x0;
    x0 += x1; x1 = rotl32(x1, 29); x1 ^= x0;
    x0 += x1; x1 = rotl32(x1, 16); x1 ^= x0;
    x0 += x1; x1 = rotl32(x1, 24); x1 ^= x0;
    x0 += ks1; x1 += ks2 + 4u;
    x0 += x1; x1 = rotl32(x1, 13); x1 ^= x0;
    x0 += x1; x1 = rotl32(x1, 15); x1 ^= x0;
    x0 += x1; x1 = rotl32(x1, 26); x1 ^= x0;
    x0 += x1; x1 = rotl32(x1,  6); x1 ^= x0;
    x0 += ks2; x1 += ks0 + 5u;
}

__device__ __forceinline__ int jax_keep_bit(int idx) {
    unsigned x0 = 0u, x1 = (unsigned)idx;
    threefry2x32(0u, 42u, x0, x1);
    unsigned bits = x0 ^ x1;
    unsigned fb = (bits >> 9) | 0x3F800000u;
    float u = __uint_as_float(fb) - 1.0f;
    return u < 0.9f ? 1 : 0;
}

__device__ __forceinline__ float dot4(float4 a, float4 b) {
    return a.x * b.x + a.y * b.y + a.z * b.z + a.w * b.w;
}

// ---------------- Phase 1: partial dots, 4-way kv split, XCD-co-located ---
// Logical work item (cb, g): all 8 q rows vs kv rows 4g..4g+3 over colblock
// cb's grid-stride columns. Swizzle so the 4 g-blocks of one cb have bids
// differing by 8 -> same XCD under round-robin dispatch -> q re-reads hit
// that XCD's 4MB L2 instead of HBM (R5 was 2x HBM overfetch from q).
__global__ __launch_bounds__(256, 4) void qk_partial_kernel(
    const float4* __restrict__ qkv, float* __restrict__ partial,
    unsigned D4, unsigned ncb)
{
    const int tid = threadIdx.x;
    const int w   = tid >> 6;
    const int lane = tid & 63;

    unsigned g, cb;
    if ((ncb & (NXCD - 1)) == 0) {
        const unsigned xcd = blockIdx.x & (NXCD - 1);
        const unsigned idx = blockIdx.x >> 3;   // [0, ncb*4/8)
        g  = idx & (NGRP - 1);
        cb = (idx >> 2) * NXCD + xcd;
    } else {
        g  = blockIdx.x & (NGRP - 1);
        cb = blockIdx.x >> 2;
    }

    const float4* __restrict__ kbase = qkv + (size_t)(NQ + g * KPG) * D4;

    float acc[NQ][KPG];
#pragma unroll
    for (int r = 0; r < NQ; ++r)
#pragma unroll
        for (int j = 0; j < KPG; ++j) acc[r][j] = 0.f;
    float nacc[NQ];
#pragma unroll
    for (int r = 0; r < NQ; ++r) nacc[r] = 0.f;

    const unsigned stride = ncb * 256u;

    for (unsigned v = cb * 256u + tid; v < D4; v += stride) {
        float4 kv[KPG];
#pragma unroll
        for (int j = 0; j < KPG; ++j)
            kv[j] = kbase[(size_t)j * D4 + v];
        float4 qv[NQ];
#pragma unroll
        for (int r = 0; r < NQ; ++r)
            qv[r] = qkv[(size_t)r * D4 + v];

        if (g == 0) {
#pragma unroll
            for (int r = 0; r < NQ; ++r)
                nacc[r] += dot4(qv[r], qv[r]);
        }
#pragma unroll
        for (int r = 0; r < NQ; ++r)
#pragma unroll
            for (int j = 0; j < KPG; ++j)
                acc[r][j] += dot4(qv[r], kv[j]);
    }

    // wave shuffle-reduce the 40 partials, then cross-wave combine via LDS
    __shared__ float lred[4][NPB];
#pragma unroll
    for (int r = 0; r < NQ; ++r) {
#pragma unroll
        for (int j = 0; j < KPG; ++j) {
            float s = acc[r][j];
#pragma unroll
            for (int off = 32; off >= 1; off >>= 1)
                s += __shfl_xor(s, off, 64);
            if (lane == 0) lred[w][r * KPG + j] = s;
        }
    }
    if (g == 0) {
#pragma unroll
        for (int r = 0; r < NQ; ++r) {
            float s = nacc[r];
#pragma unroll
            for (int off = 32; off >= 1; off >>= 1)
                s += __shfl_xor(s, off, 64);
            if (lane == 0) lred[w][32 + r] = s;
        }
    } else if (lane == 0) {
#pragma unroll
        for (int r = 0; r < NQ; ++r) lred[w][32 + r] = 0.f;
    }
    __syncthreads();
    if (tid < NPB) {
        const float s = lred[0][tid] + lred[1][tid] + lred[2][tid] + lred[3][tid];
        partial[(size_t)(cb * NGRP + g) * NPB + tid] = s;  // logical index
    }
}

// ---------------- Phase 2: reduce partials across colblocks ---------------
__global__ __launch_bounds__(256) void reduce_kernel(
    const float* __restrict__ partial, float* __restrict__ sums, int ncb)
{
    const int s = blockIdx.x;  // 0..135
    int g, slot;
    if (s < 128) {
        const int r = s >> 4, j = s & 15;
        g = j >> 2; slot = r * KPG + (j & 3);
    } else {
        g = 0; slot = 32 + (s - 128);
    }

    float acc = 0.f;
    for (int cb = threadIdx.x; cb < ncb; cb += 256)
        acc += partial[(size_t)(cb * NGRP + g) * NPB + slot];

    float vsum = acc;
    for (int off = 32; off >= 1; off >>= 1)
        vsum += __shfl_xor(vsum, off, 64);

    __shared__ float red[4];
    const int w = threadIdx.x >> 6, lane = threadIdx.x & 63;
    if (lane == 0) red[w] = vsum;
    __syncthreads();
    if (threadIdx.x == 0) sums[s] = red[0] + red[1] + red[2] + red[3];
}

// ---------------- Phase 3: scale, softmax, dropout ------------------------
__global__ __launch_bounds__(128) void finalize_kernel(
    const float* __restrict__ sums, float* __restrict__ out)
{
    const int idx = threadIdx.x;  // 0..127
    const int r = idx >> 4;

    const float norm = sums[128 + r];
    const float inv_scale = rsqrtf(norm + 1e-12f);
    const float logit = sums[idx] * inv_scale;

    float m = logit;
    for (int off = 8; off >= 1; off >>= 1)
        m = fmaxf(m, __shfl_xor(m, off, 64));
    const float e = expf(logit - m);
    float ssum = e;
    for (int off = 8; off >= 1; off >>= 1)
        ssum += __shfl_xor(ssum, off, 64);
    const float sm = e / ssum;

    out[idx] = jax_keep_bit(idx) ? (sm / 0.9f) : 0.f;
}

// ---------------- Launch --------------------------------------------------
extern "C" void kernel_launch(void* const* d_in, const int* in_sizes, int n_in,
                              void* d_out, int out_size, void* d_ws, size_t ws_size,
                              hipStream_t stream) {
    const float* qkv = (const float*)d_in[0];
    float* out = (float*)d_out;

    const long long total = (long long)in_sizes[0];
    const unsigned D  = (unsigned)(total / (NQ + NKV));
    const unsigned D4 = D / 4;

    float* wsf = (float*)d_ws;
    const long long cap_floats = (long long)(ws_size / 4);

    unsigned ncb = 256;  // 256 colblocks x 4 groups = 1024 blocks, 1 round
    long long need = (long long)ncb * NGRP * NPB + NSUM;
    while (need > cap_floats && ncb > 1) {
        ncb >>= 1;
        need = (long long)ncb * NGRP * NPB + NSUM;
    }

    float* partial = wsf;
    float* sums    = wsf + (long long)ncb * NGRP * NPB;

    qk_partial_kernel<<<ncb * NGRP, 256, 0, stream>>>(
        (const float4*)qkv, partial, D4, ncb);
    reduce_kernel<<<NSUM, 256, 0, stream>>>(partial, sums, (int)ncb);
    finalize_kernel<<<1, 128, 0, stream>>>(sums, out);
}